// Round 7
// baseline (1068.758 us; speedup 1.0000x reference)
//
#include <hip/hip_runtime.h>
#include <hip/hip_bf16.h>
#include <math.h>

#define N_NODES   100000
#define N_EDGES   600000
#define NG        64
#define H         128
#define STEPS     4
#define FB        90
#define FV        20
#define NN        (2*N_NODES)   /* 200000 combined nodes */
#define EE        (2*N_EDGES)   /* 1200000 combined edges */
#define BSTR      40            /* LDS row stride in shorts for A tiles */
#define NBLK      196           /* scan blocks: 196*1024 = 200704 >= NN */
#define NNP       (NBLK*1024)   /* padded degree array length */
#define NBUCK     (NN/64)       /* 3125 CSR fill buckets (64 nodes each) */

#define WCAT_KC   (12*64*8)       /* shorts per (s,b1,kc) fragment chunk = 6144 (12KB) */
#define WCAT_HALF (8*WCAT_KC)     /* per (s,b1) */
#define WCAT_STEP (2*WCAT_HALF)   /* per step  */

typedef unsigned short u16;
typedef __attribute__((ext_vector_type(8))) __bf16 bf16x8;
typedef __attribute__((ext_vector_type(4))) float  floatx4;

static __device__ __forceinline__ float bf16_lo(unsigned u){ return __uint_as_float(u << 16); }
static __device__ __forceinline__ float bf16_hi(unsigned u){ return __uint_as_float(u & 0xffff0000u); }
static __device__ __forceinline__ u16 f2bf(float f){
    union { float f; unsigned u; } v; v.f = f;
    unsigned r = v.u + 0x7fffu + ((v.u >> 16) & 1u);
    return (u16)(r >> 16);
}
static __device__ __forceinline__ float fastrcp(float x){ return __builtin_amdgcn_rcpf(x); }
static __device__ __forceinline__ float fsigmoid(float x){ return fastrcp(1.f + __expf(-x)); }
static __device__ __forceinline__ float ftanh(float x){ return 1.f - 2.f*fastrcp(1.f + __expf(2.f*x)); }

// ---------------- CSR construction ----------------

__global__ void deg_kernel(const int* __restrict__ eib, const int* __restrict__ eiv,
                           int* __restrict__ deg){
    int e = blockIdx.x*blockDim.x + threadIdx.x;
    if (e >= EE) return;
    int d;
    if (e < N_EDGES) d = eib[N_EDGES + e];
    else             d = eiv[N_EDGES + (e - N_EDGES)] + N_NODES;
    atomicAdd(&deg[d], 1);
}

__global__ __launch_bounds__(256) void bsum_kernel(const int* __restrict__ deg, int* __restrict__ bsum){
    int t = threadIdx.x;
    int4 v = reinterpret_cast<const int4*>(deg)[blockIdx.x*256 + t];
    int s = v.x + v.y + v.z + v.w;
    __shared__ int ss[256];
    ss[t] = s; __syncthreads();
    for (int off = 128; off > 0; off >>= 1){ if (t < off) ss[t] += ss[t + off]; __syncthreads(); }
    if (t == 0) bsum[blockIdx.x] = ss[0];
}

__global__ __launch_bounds__(256) void bscan_kernel(const int* __restrict__ bsum, int* __restrict__ boff){
    int t = threadIdx.x;
    int v = (t < NBLK) ? bsum[t] : 0;
    __shared__ int ss[256];
    ss[t] = v; __syncthreads();
    for (int off = 1; off < 256; off <<= 1){
        int u = (t >= off) ? ss[t - off] : 0;
        __syncthreads();
        ss[t] += u;
        __syncthreads();
    }
    boff[t] = ss[t] - v;   // exclusive
}

__global__ __launch_bounds__(256) void scan_final_kernel(const int* __restrict__ deg, const int* __restrict__ boff,
                                                         int* __restrict__ row_ptr){
    int t = threadIdx.x, b = blockIdx.x;
    int4 v = reinterpret_cast<const int4*>(deg)[b*256 + t];
    int s = v.x + v.y + v.z + v.w;
    __shared__ int ss[256];
    ss[t] = s; __syncthreads();
    for (int off = 1; off < 256; off <<= 1){
        int u = (t >= off) ? ss[t - off] : 0;
        __syncthreads();
        ss[t] += u;
        __syncthreads();
    }
    int base = boff[b] + ss[t] - s;
    int i0 = b*1024 + t*4;
    int e0 = base, e1 = e0 + v.x, e2 = e1 + v.y, e3 = e2 + v.z;
    if (i0 < NN){
        reinterpret_cast<int4*>(row_ptr)[i0 >> 2] = make_int4(e0, e1, e2, e3);
    }
    if (b == 0 && t == 0) row_ptr[NN] = EE;
}

// bucket cursors start at each bucket's csr region base
__global__ void bcur_init_kernel(const int* __restrict__ row_ptr, int* __restrict__ bcur){
    int b = blockIdx.x*blockDim.x + threadIdx.x;
    if (b < NBUCK) bcur[b] = row_ptr[b*64];
}

// Pass 1: append (src<<6)|(dst&63) into bucket region. Blocks only handle
// buckets with (bucket&7)==blockIdx%8 -> (heuristically) XCD-local L2 write
// frontiers, so the ~200KB of active lines merge instead of thrashing.
// Correct for ANY block->XCD mapping (each edge matches exactly one group).
__global__ __launch_bounds__(256) void bucket_fill_kernel(const int* __restrict__ eib, const int* __restrict__ eiv,
                                                          int* __restrict__ bcur, int* __restrict__ bucket_buf){
    int g   = blockIdx.x & 7;
    int bid = blockIdx.x >> 3;
    int nb  = gridDim.x >> 3;
    for (int e = bid*256 + threadIdx.x; e < EE; e += nb*256){
        int s, d;
        if (e < N_EDGES){ s = eib[e];                 d = eib[N_EDGES + e]; }
        else { int e2 = e - N_EDGES; s = eiv[e2] + N_NODES; d = eiv[N_EDGES + e2] + N_NODES; }
        int b = d >> 6;
        if ((b & 7) == g){
            int pos = atomicAdd(&bcur[b], 1);
            bucket_buf[pos] = (s << 6) | (d & 63);
        }
    }
}

// Pass 2: one block per bucket; LDS cursors for its 64 nodes; dense writes
// into the bucket's contiguous csr_src region.
__global__ __launch_bounds__(256) void bucket_scatter_kernel(const int* __restrict__ bucket_buf,
                                                             const int* __restrict__ row_ptr,
                                                             int* __restrict__ csr_src){
    __shared__ int cur[64];
    int b = blockIdx.x, t = threadIdx.x;
    int base = row_ptr[b*64];
    int cnt  = row_ptr[b*64 + 64] - base;
    if (t < 64) cur[t] = row_ptr[b*64 + t];
    __syncthreads();
    for (int i = t; i < cnt; i += 256){
        int entry = bucket_buf[base + i];
        int d = entry & 63, s = entry >> 6;
        int pos = atomicAdd(&cur[d], 1);
        csr_src[pos] = s;
    }
}

// ---------------- weight prep ----------------
// Fold the GGC weight into the GRU input weights (linearity of segment_sum):
//   Bfold[s][k][c] = sum_q Wg[s][k][q] * w_ih[c][q],  k in [0,128), c in [0,384)
__global__ __launch_bounds__(128) void fold_kernel(const float* __restrict__ ggc_w,
                                                   const float* __restrict__ w_ih,
                                                   float* __restrict__ Bfold){
    int blk = blockIdx.x;              // s*128 + k
    int s = blk >> 7, k = blk & 127;
    __shared__ float wg[128];
    int t = threadIdx.x;
    wg[t] = ggc_w[(size_t)s*H*H + (size_t)k*H + t];
    __syncthreads();
    for (int c = t; c < 384; c += 128){
        const float* wr = w_ih + (size_t)c*H;
        float acc = 0.f;
        for (int q = 0; q < 128; q += 4){
            float4 a = *reinterpret_cast<const float4*>(&wg[q]);
            float4 b = *reinterpret_cast<const float4*>(&wr[q]);
            acc += a.x*b.x + a.y*b.y + a.z*b.z + a.w*b.w;
        }
        Bfold[((size_t)s*H + k)*384 + c] = acc;
    }
}

// Pack B into fragment-major layout: Wcat[s][b1][kc][t(12)][lane(64)][v(8)]
__global__ void pack_kernel(const float* __restrict__ Bfold, const float* __restrict__ w_hh,
                            u16* __restrict__ Wcat){
    int idx = blockIdx.x*256 + threadIdx.x;
    if (idx >= STEPS*WCAT_STEP) return;
    int v    = idx & 7;
    int lane = (idx >> 3) & 63;
    int t    = (idx >> 9) % 12;
    int rem  = idx / (512*12);          // s*16 + b1*8 + kc
    int kc   = rem & 7;
    int b1   = (rem >> 3) & 1;
    int s    = rem >> 4;
    int col16 = lane & 15, l4 = lane >> 4;
    int k = kc*32 + l4*8 + v;
    int g = t >> 2, jj = t & 3;
    int c = (4*b1 + jj)*16 + col16;
    int gc = (g == 2) ? (256 + c) : (g*128 + c);
    float val;
    if (k < 128) val = Bfold[((size_t)s*H + k)*384 + gc];
    else         val = w_hh[(size_t)gc*H + (k - 128)];
    Wcat[idx] = f2bf(val);
}

// ---------------- embedding: hb = bf16(relu(x @ W_emb)) ----------------

__global__ __launch_bounds__(128) void emb_kernel(const float* __restrict__ xb, const float* __restrict__ xv,
                                                  const float* __restrict__ Wb, const float* __restrict__ Wv,
                                                  u16* __restrict__ hb){
    __shared__ float xs[8][FB];
    int j = threadIdx.x;
    int n0 = blockIdx.x * 8;
    const float* x; const float* W; int K; int xoff;
    if (n0 < N_NODES){ x = xb; W = Wb; K = FB; xoff = n0; }
    else             { x = xv; W = Wv; K = FV; xoff = n0 - N_NODES; }
    for (int i = j; i < 8*K; i += 128){ int r = i / K, c = i - r*K; xs[r][c] = x[(xoff + r)*K + c]; }
    __syncthreads();
    float acc[8];
    #pragma unroll
    for (int n = 0; n < 8; ++n) acc[n] = 0.f;
    for (int k = 0; k < K; ++k){
        float w = W[k*H + j];
        #pragma unroll
        for (int n = 0; n < 8; ++n) acc[n] = fmaf(xs[n][k], w, acc[n]);
    }
    #pragma unroll
    for (int n = 0; n < 8; ++n)
        hb[(size_t)(n0 + n)*H + j] = f2bf(fmaxf(acc[n], 0.f));
}

// ---------------- agg_raw[dst] = sum hb[src] ----------------
// One wave per node. 16 lanes cover a row (uint4 = 16B/lane); 4 quarter-waves
// process 4 edges in parallel; 2x unroll -> 8 edges / loop iteration.
// Cross-quarter combine via shfl_xor(16) + shfl_xor(32).

__global__ __launch_bounds__(256) void agg_kernel(const u16* __restrict__ hb,
                                                  const int* __restrict__ row_ptr,
                                                  const int* __restrict__ csr_src,
                                                  u16* __restrict__ aggb){
    int wid  = threadIdx.x >> 6;
    int lane = threadIdx.x & 63;
    int q    = lane >> 4;          // 0..3: edge slot
    int c    = lane & 15;          // uint4 index within the row
    int node = blockIdx.x*4 + wid;
    int beg = row_ptr[node], end = row_ptr[node+1];
    const uint4* rows = reinterpret_cast<const uint4*>(hb);
    float s0=0.f,s1=0.f,s2=0.f,s3=0.f,s4=0.f,s5=0.f,s6=0.f,s7=0.f;
    float u0=0.f,u1=0.f,u2=0.f,u3=0.f,u4=0.f,u5=0.f,u6=0.f,u7=0.f;
    int e = beg + q;
    for (; e + 4 < end; e += 8){
        int sA = csr_src[e];
        int sB = csr_src[e + 4];
        uint4 a = rows[(size_t)sA*16 + c];
        uint4 b = rows[(size_t)sB*16 + c];
        s0 += bf16_lo(a.x); s1 += bf16_hi(a.x); s2 += bf16_lo(a.y); s3 += bf16_hi(a.y);
        s4 += bf16_lo(a.z); s5 += bf16_hi(a.z); s6 += bf16_lo(a.w); s7 += bf16_hi(a.w);
        u0 += bf16_lo(b.x); u1 += bf16_hi(b.x); u2 += bf16_lo(b.y); u3 += bf16_hi(b.y);
        u4 += bf16_lo(b.z); u5 += bf16_hi(b.z); u6 += bf16_lo(b.w); u7 += bf16_hi(b.w);
    }
    if (e < end){
        int sA = csr_src[e];
        uint4 a = rows[(size_t)sA*16 + c];
        s0 += bf16_lo(a.x); s1 += bf16_hi(a.x); s2 += bf16_lo(a.y); s3 += bf16_hi(a.y);
        s4 += bf16_lo(a.z); s5 += bf16_hi(a.z); s6 += bf16_lo(a.w); s7 += bf16_hi(a.w);
    }
    s0 += u0; s1 += u1; s2 += u2; s3 += u3; s4 += u4; s5 += u5; s6 += u6; s7 += u7;
    s0 += __shfl_xor(s0, 16); s1 += __shfl_xor(s1, 16); s2 += __shfl_xor(s2, 16); s3 += __shfl_xor(s3, 16);
    s4 += __shfl_xor(s4, 16); s5 += __shfl_xor(s5, 16); s6 += __shfl_xor(s6, 16); s7 += __shfl_xor(s7, 16);
    s0 += __shfl_xor(s0, 32); s1 += __shfl_xor(s1, 32); s2 += __shfl_xor(s2, 32); s3 += __shfl_xor(s3, 32);
    s4 += __shfl_xor(s4, 32); s5 += __shfl_xor(s5, 32); s6 += __shfl_xor(s6, 32); s7 += __shfl_xor(s7, 32);
    if (q == 0){
        uint4 o;
        o.x = (unsigned)f2bf(s0) | ((unsigned)f2bf(s1) << 16);
        o.y = (unsigned)f2bf(s2) | ((unsigned)f2bf(s3) << 16);
        o.z = (unsigned)f2bf(s4) | ((unsigned)f2bf(s5) << 16);
        o.w = (unsigned)f2bf(s6) | ((unsigned)f2bf(s7) << 16);
        reinterpret_cast<uint4*>(aggb)[(size_t)node*16 + c] = o;
    }
}

// ---------------- fused GRU via MFMA (bf16 state, fast gate math) ----------------
// grid (NN/64, 2). Block: 64 rows x 256 B-cols. 16 acc tiles = 64 AGPR.

__global__ __launch_bounds__(256, 3) void gru_mfma_kernel(const u16* __restrict__ aggb,
                                                          const u16* __restrict__ hb_in,
                                                          u16* __restrict__ hb_out,
                                                          const u16* __restrict__ Wcat,  /* this step: [2][8][12][64][8] */
                                                          const float* __restrict__ b_ih,
                                                          const float* __restrict__ b_hh){
    __shared__ u16 Bs[WCAT_KC];      // 12 KB, fragment-major
    __shared__ u16 As[64*BSTR];      // 5 KB
    const int t = threadIdx.x;
    const int wid = t >> 6, lane = t & 63;
    const int l15 = lane & 15, l4 = lane >> 4;
    const int n0 = blockIdx.x * 64;
    const int b1 = blockIdx.y;
    const u16* Wsrc = Wcat + (size_t)b1*WCAT_HALF;

    floatx4 accR[4], accZ[4], accNi[4], accNh[4];
    #pragma unroll
    for (int i = 0; i < 4; ++i){
        accR[i] = (floatx4){0.f,0.f,0.f,0.f};  accZ[i]  = (floatx4){0.f,0.f,0.f,0.f};
        accNi[i] = (floatx4){0.f,0.f,0.f,0.f}; accNh[i] = (floatx4){0.f,0.f,0.f,0.f};
    }

    for (int kc = 0; kc < 8; ++kc){
        __syncthreads();
        {   // stage B: 768 int4, fragment-major -> fully coalesced, conflict-free
            const u16* src = Wsrc + (size_t)kc*WCAT_KC;
            #pragma unroll
            for (int p = 0; p < 3; ++p){
                int i = t + p*256;
                *reinterpret_cast<int4*>(&Bs[i*8]) = *reinterpret_cast<const int4*>(src + (size_t)i*8);
            }
        }
        {   // stage A: 64 rows x 32 shorts
            int row = t >> 2, part = t & 3;
            const u16* srcA = (kc < 4) ? aggb : hb_in;
            const int4 v = *reinterpret_cast<const int4*>(srcA + (size_t)(n0 + row)*H + (kc & 3)*32 + part*8);
            *reinterpret_cast<int4*>(&As[row*BSTR + part*8]) = v;
        }
        __syncthreads();
        bf16x8 aF = *reinterpret_cast<const bf16x8*>(&As[(wid*16 + l15)*BSTR + l4*8]);
        if (kc < 4){
            #pragma unroll
            for (int j = 0; j < 4; ++j){
                bf16x8 bR = *reinterpret_cast<const bf16x8*>(&Bs[((0*4 + j)*64 + lane)*8]);
                bf16x8 bZ = *reinterpret_cast<const bf16x8*>(&Bs[((1*4 + j)*64 + lane)*8]);
                bf16x8 bN = *reinterpret_cast<const bf16x8*>(&Bs[((2*4 + j)*64 + lane)*8]);
                accR[j]  = __builtin_amdgcn_mfma_f32_16x16x32_bf16(aF, bR, accR[j], 0, 0, 0);
                accZ[j]  = __builtin_amdgcn_mfma_f32_16x16x32_bf16(aF, bZ, accZ[j], 0, 0, 0);
                accNi[j] = __builtin_amdgcn_mfma_f32_16x16x32_bf16(aF, bN, accNi[j], 0, 0, 0);
            }
        } else {
            #pragma unroll
            for (int j = 0; j < 4; ++j){
                bf16x8 bR = *reinterpret_cast<const bf16x8*>(&Bs[((0*4 + j)*64 + lane)*8]);
                bf16x8 bZ = *reinterpret_cast<const bf16x8*>(&Bs[((1*4 + j)*64 + lane)*8]);
                bf16x8 bN = *reinterpret_cast<const bf16x8*>(&Bs[((2*4 + j)*64 + lane)*8]);
                accR[j]  = __builtin_amdgcn_mfma_f32_16x16x32_bf16(aF, bR, accR[j], 0, 0, 0);
                accZ[j]  = __builtin_amdgcn_mfma_f32_16x16x32_bf16(aF, bZ, accZ[j], 0, 0, 0);
                accNh[j] = __builtin_amdgcn_mfma_f32_16x16x32_bf16(aF, bN, accNh[j], 0, 0, 0);
            }
        }
    }

    const int rowb = n0 + wid*16 + l4*4;
    #pragma unroll
    for (int jj = 0; jj < 4; ++jj){
        int col = (4*b1 + jj)*16 + l15;
        float br  = b_ih[col]       + b_hh[col];
        float bz  = b_ih[128 + col] + b_hh[128 + col];
        float bin = b_ih[256 + col];
        float bhn = b_hh[256 + col];
        #pragma unroll
        for (int rg = 0; rg < 4; ++rg){
            int row = rowb + rg;
            float r   = fsigmoid(accR[jj][rg] + br);
            float z   = fsigmoid(accZ[jj][rg] + bz);
            float nn_ = ftanh(accNi[jj][rg] + bin + r*(accNh[jj][rg] + bhn));
            float hold = bf16_lo((unsigned)hb_in[(size_t)row*H + col]);
            float hnew = (1.f - z)*nn_ + z*hold;
            hb_out[(size_t)row*H + col] = f2bf(hnew);
        }
    }
}

// ---------------- pooling (bf16 state in) ----------------

__global__ __launch_bounds__(128) void pool_kernel(const u16* __restrict__ hb,
                                                   const int* __restrict__ batch_b, const int* __restrict__ batch_v,
                                                   float* __restrict__ pool){
    int j  = threadIdx.x;
    int n0 = blockIdx.x * 32;
    bool voro = (n0 >= N_NODES);
    int colbase = voro ? 128 : 0;
    int gcur = -1; float acc = 0.f;
    for (int r = 0; r < 32; ++r){
        int node = n0 + r;
        int g = voro ? batch_v[node - N_NODES] : batch_b[node];
        if (g != gcur){
            if (gcur >= 0) atomicAdd(&pool[gcur*256 + colbase + j], acc);
            acc = 0.f; gcur = g;
        }
        acc += fmaxf(bf16_lo((unsigned)hb[(size_t)node*H + j]), 0.f);
    }
    if (gcur >= 0) atomicAdd(&pool[gcur*256 + colbase + j], acc);
}

__global__ __launch_bounds__(256) void cnt_kernel(const int* __restrict__ batch_b, const int* __restrict__ batch_v,
                                                  int* __restrict__ cnt){
    __shared__ int bins[128];
    int t = threadIdx.x;
    if (t < 128) bins[t] = 0;
    __syncthreads();
    int i = blockIdx.x*256 + t;
    if (i < NN){
        int g = (i < N_NODES) ? batch_b[i] : 64 + batch_v[i - N_NODES];
        atomicAdd(&bins[g], 1);
    }
    __syncthreads();
    if (t < 128 && bins[t] > 0) atomicAdd(&cnt[t], bins[t]);
}

// ---------------- output head ----------------

__global__ __launch_bounds__(256) void head_kernel(const float* __restrict__ pool, const int* __restrict__ cnt,
                                                   const float* __restrict__ W1, const float* __restrict__ b1,
                                                   const float* __restrict__ W2, const float* __restrict__ b2,
                                                   float* __restrict__ out){
    __shared__ float gs[256];
    __shared__ float wsum[4];
    int b = blockIdx.x, j = threadIdx.x;
    int c = (j < 128) ? cnt[b] : cnt[64 + b];
    float denom = (float)((c > 1) ? c : 1);
    gs[j] = pool[b*256 + j] / denom;
    __syncthreads();
    float acc = b1[j];
    for (int k = 0; k < 256; ++k) acc = fmaf(gs[k], W1[k*256 + j], acc);
    float y = fmaxf(acc, 0.f) * W2[j];
    #pragma unroll
    for (int off = 32; off > 0; off >>= 1) y += __shfl_down(y, off, 64);
    if ((j & 63) == 0) wsum[j >> 6] = y;
    __syncthreads();
    if (j == 0){
        float x = wsum[0] + wsum[1] + wsum[2] + wsum[3] + b2[0];
        float sp = (x > 0.f) ? x + log1pf(expf(-x)) : log1pf(expf(x));
        out[b] = sp;
    }
}

// ---------------- launch ----------------

extern "C" void kernel_launch(void* const* d_in, const int* in_sizes, int n_in,
                              void* d_out, int out_size, void* d_ws, size_t ws_size,
                              hipStream_t stream){
    const float* x_b      = (const float*)d_in[0];
    const int*   eib      = (const int*)  d_in[1];
    const int*   batch_b  = (const int*)  d_in[2];
    const float* x_v      = (const float*)d_in[3];
    const int*   eiv      = (const int*)  d_in[4];
    const int*   batch_v  = (const int*)  d_in[5];
    const float* W_emb_b  = (const float*)d_in[6];
    const float* W_emb_v  = (const float*)d_in[7];
    const float* ggc_w    = (const float*)d_in[8];
    const float* gru_w_ih = (const float*)d_in[9];
    const float* gru_w_hh = (const float*)d_in[10];
    const float* gru_b_ih = (const float*)d_in[11];
    const float* gru_b_hh = (const float*)d_in[12];
    const float* W1       = (const float*)d_in[13];
    const float* b1       = (const float*)d_in[14];
    const float* W2       = (const float*)d_in[15];
    const float* b2       = (const float*)d_in[16];
    float* out = (float*)d_out;

    char* ws = (char*)d_ws;
    size_t off = 0;
    auto alloc = [&](size_t bytes)->char*{
        char* p = ws + off; off += (bytes + 255)/256*256; return p;
    };
    u16*   hb0      = (u16*)   alloc((size_t)NN*H*2);        //  51.2 MB
    u16*   hb1      = (u16*)   alloc((size_t)NN*H*2);        //  51.2 MB
    u16*   aggb     = (u16*)   alloc((size_t)NN*H*2);        //  51.2 MB
    float* Bfold    = (float*) alloc((size_t)STEPS*H*384*4); // 786 KB
    u16*   Wcat     = (u16*)   alloc((size_t)STEPS*WCAT_STEP*2);
    int*   row_ptr  = (int*)   alloc((size_t)(NN+1)*4);
    int*   deg      = (int*)   alloc((size_t)NNP*4);
    int*   csr_src  = (int*)   alloc((size_t)EE*4);
    int*   bucket_buf = (int*) alloc((size_t)EE*4);
    int*   bcur     = (int*)   alloc((size_t)NBUCK*4);
    int*   bsum     = (int*)   alloc((size_t)256*4);
    int*   boff     = (int*)   alloc((size_t)256*4);
    float* pool     = (float*) alloc((size_t)NG*2*H*4);
    int*   cnt      = (int*)   alloc((size_t)2*NG*4);
    (void)ws_size; (void)in_sizes; (void)n_in; (void)out_size;

    hipMemsetAsync(deg,  0, (size_t)NNP*4, stream);
    hipMemsetAsync(pool, 0, (size_t)NG*2*H*4, stream);
    hipMemsetAsync(cnt,  0, (size_t)2*NG*4, stream);

    deg_kernel           <<<(EE + 255)/256, 256, 0, stream>>>(eib, eiv, deg);
    bsum_kernel          <<<NBLK, 256, 0, stream>>>(deg, bsum);
    bscan_kernel         <<<1, 256, 0, stream>>>(bsum, boff);
    scan_final_kernel    <<<NBLK, 256, 0, stream>>>(deg, boff, row_ptr);
    bcur_init_kernel     <<<(NBUCK + 255)/256, 256, 0, stream>>>(row_ptr, bcur);
    bucket_fill_kernel   <<<2048, 256, 0, stream>>>(eib, eiv, bcur, bucket_buf);
    bucket_scatter_kernel<<<NBUCK, 256, 0, stream>>>(bucket_buf, row_ptr, csr_src);
    fold_kernel          <<<STEPS*H, 128, 0, stream>>>(ggc_w, gru_w_ih, Bfold);
    pack_kernel          <<<(STEPS*WCAT_STEP + 255)/256, 256, 0, stream>>>(Bfold, gru_w_hh, Wcat);

    emb_kernel<<<NN/8, 128, 0, stream>>>(x_b, x_v, W_emb_b, W_emb_v, hb0);

    u16* hbs[2] = { hb0, hb1 };
    for (int s = 0; s < STEPS; ++s){
        u16* hin  = hbs[s & 1];
        u16* hout = hbs[(s + 1) & 1];
        agg_kernel     <<<NN/4, 256, 0, stream>>>(hin, row_ptr, csr_src, aggb);
        gru_mfma_kernel<<<dim3(NN/64, 2), 256, 0, stream>>>(aggb, hin, hout,
                                                            Wcat + (size_t)s*WCAT_STEP,
                                                            gru_b_ih, gru_b_hh);
    }

    pool_kernel<<<NN/32, 128, 0, stream>>>(hb0, batch_b, batch_v, pool);
    cnt_kernel <<<(NN + 255)/256, 256, 0, stream>>>(batch_b, batch_v, cnt);
    head_kernel<<<NG, 256, 0, stream>>>(pool, cnt, W1, b1, W2, b2, out);
}

// Round 8
// 955.733 us; speedup vs baseline: 1.1183x; 1.1183x over previous
//
#include <hip/hip_runtime.h>
#include <hip/hip_bf16.h>
#include <math.h>

#define N_NODES   100000
#define N_EDGES   600000
#define NG        64
#define H         128
#define STEPS     4
#define FB        90
#define FV        20
#define NN        (2*N_NODES)   /* 200000 combined nodes */
#define EE        (2*N_EDGES)   /* 1200000 combined edges */
#define BSTR      40            /* LDS row stride in shorts for A tiles */
#define NBLK      196           /* scan blocks: 196*1024 = 200704 >= NN */
#define NNP       (NBLK*1024)   /* padded degree array length */

#define WCAT_KC   (12*64*8)       /* shorts per (s,b1,kc) fragment chunk = 6144 (12KB) */
#define WCAT_HALF (8*WCAT_KC)     /* per (s,b1) */
#define WCAT_STEP (2*WCAT_HALF)   /* per step  */

typedef unsigned short u16;
typedef __attribute__((ext_vector_type(8))) __bf16 bf16x8;
typedef __attribute__((ext_vector_type(4))) float  floatx4;

static __device__ __forceinline__ float bf16_lo(unsigned u){ return __uint_as_float(u << 16); }
static __device__ __forceinline__ float bf16_hi(unsigned u){ return __uint_as_float(u & 0xffff0000u); }
static __device__ __forceinline__ u16 f2bf(float f){
    union { float f; unsigned u; } v; v.f = f;
    unsigned r = v.u + 0x7fffu + ((v.u >> 16) & 1u);
    return (u16)(r >> 16);
}
static __device__ __forceinline__ float fastrcp(float x){ return __builtin_amdgcn_rcpf(x); }
static __device__ __forceinline__ float fsigmoid(float x){ return fastrcp(1.f + __expf(-x)); }
static __device__ __forceinline__ float ftanh(float x){ return 1.f - 2.f*fastrcp(1.f + __expf(2.f*x)); }

// ---------------- CSR construction (R6 direct-scatter version: measured 86us) ----------------

__global__ void deg_kernel(const int* __restrict__ eib, const int* __restrict__ eiv,
                           int* __restrict__ deg){
    int e = blockIdx.x*blockDim.x + threadIdx.x;
    if (e >= EE) return;
    int d;
    if (e < N_EDGES) d = eib[N_EDGES + e];
    else             d = eiv[N_EDGES + (e - N_EDGES)] + N_NODES;
    atomicAdd(&deg[d], 1);
}

__global__ __launch_bounds__(256) void bsum_kernel(const int* __restrict__ deg, int* __restrict__ bsum){
    int t = threadIdx.x;
    int4 v = reinterpret_cast<const int4*>(deg)[blockIdx.x*256 + t];
    int s = v.x + v.y + v.z + v.w;
    __shared__ int ss[256];
    ss[t] = s; __syncthreads();
    for (int off = 128; off > 0; off >>= 1){ if (t < off) ss[t] += ss[t + off]; __syncthreads(); }
    if (t == 0) bsum[blockIdx.x] = ss[0];
}

__global__ __launch_bounds__(256) void bscan_kernel(const int* __restrict__ bsum, int* __restrict__ boff){
    int t = threadIdx.x;
    int v = (t < NBLK) ? bsum[t] : 0;
    __shared__ int ss[256];
    ss[t] = v; __syncthreads();
    for (int off = 1; off < 256; off <<= 1){
        int u = (t >= off) ? ss[t - off] : 0;
        __syncthreads();
        ss[t] += u;
        __syncthreads();
    }
    boff[t] = ss[t] - v;   // exclusive
}

__global__ __launch_bounds__(256) void scan_final_kernel(const int* __restrict__ deg, const int* __restrict__ boff,
                                                         int* __restrict__ row_ptr, int* __restrict__ cursor){
    int t = threadIdx.x, b = blockIdx.x;
    int4 v = reinterpret_cast<const int4*>(deg)[b*256 + t];
    int s = v.x + v.y + v.z + v.w;
    __shared__ int ss[256];
    ss[t] = s; __syncthreads();
    for (int off = 1; off < 256; off <<= 1){
        int u = (t >= off) ? ss[t - off] : 0;
        __syncthreads();
        ss[t] += u;
        __syncthreads();
    }
    int base = boff[b] + ss[t] - s;
    int i0 = b*1024 + t*4;
    int e0 = base, e1 = e0 + v.x, e2 = e1 + v.y, e3 = e2 + v.z;
    if (i0 < NN){
        int4 w = make_int4(e0, e1, e2, e3);
        reinterpret_cast<int4*>(row_ptr)[i0 >> 2] = w;
        reinterpret_cast<int4*>(cursor)[i0 >> 2]  = w;
    }
    if (b == 0 && t == 0) row_ptr[NN] = EE;
}

__global__ void csr_fill_kernel(const int* __restrict__ eib, const int* __restrict__ eiv,
                                int* __restrict__ cursor, int* __restrict__ csr_src){
    int e = blockIdx.x*blockDim.x + threadIdx.x;
    if (e >= EE) return;
    int s, d;
    if (e < N_EDGES){ s = eib[e];                 d = eib[N_EDGES + e]; }
    else { int e2 = e - N_EDGES; s = eiv[e2] + N_NODES; d = eiv[N_EDGES + e2] + N_NODES; }
    int pos = atomicAdd(&cursor[d], 1);
    csr_src[pos] = s;
}

// ---------------- weight prep ----------------
// Fold the GGC weight into the GRU input weights (linearity of segment_sum):
//   Bfold[s][k][c] = sum_q Wg[s][k][q] * w_ih[c][q],  k in [0,128), c in [0,384)
__global__ __launch_bounds__(128) void fold_kernel(const float* __restrict__ ggc_w,
                                                   const float* __restrict__ w_ih,
                                                   float* __restrict__ Bfold){
    int blk = blockIdx.x;              // s*128 + k
    int s = blk >> 7, k = blk & 127;
    __shared__ float wg[128];
    int t = threadIdx.x;
    wg[t] = ggc_w[(size_t)s*H*H + (size_t)k*H + t];
    __syncthreads();
    for (int c = t; c < 384; c += 128){
        const float* wr = w_ih + (size_t)c*H;
        float acc = 0.f;
        for (int q = 0; q < 128; q += 4){
            float4 a = *reinterpret_cast<const float4*>(&wg[q]);
            float4 b = *reinterpret_cast<const float4*>(&wr[q]);
            acc += a.x*b.x + a.y*b.y + a.z*b.z + a.w*b.w;
        }
        Bfold[((size_t)s*H + k)*384 + c] = acc;
    }
}

// Pack B into fragment-major layout: Wcat[s][b1][kc][t(12)][lane(64)][v(8)]
__global__ void pack_kernel(const float* __restrict__ Bfold, const float* __restrict__ w_hh,
                            u16* __restrict__ Wcat){
    int idx = blockIdx.x*256 + threadIdx.x;
    if (idx >= STEPS*WCAT_STEP) return;
    int v    = idx & 7;
    int lane = (idx >> 3) & 63;
    int t    = (idx >> 9) % 12;
    int rem  = idx / (512*12);          // s*16 + b1*8 + kc
    int kc   = rem & 7;
    int b1   = (rem >> 3) & 1;
    int s    = rem >> 4;
    int col16 = lane & 15, l4 = lane >> 4;
    int k = kc*32 + l4*8 + v;
    int g = t >> 2, jj = t & 3;
    int c = (4*b1 + jj)*16 + col16;
    int gc = (g == 2) ? (256 + c) : (g*128 + c);
    float val;
    if (k < 128) val = Bfold[((size_t)s*H + k)*384 + gc];
    else         val = w_hh[(size_t)gc*H + (k - 128)];
    Wcat[idx] = f2bf(val);
}

// ---------------- embedding: hb = bf16(relu(x @ W_emb)) ----------------

__global__ __launch_bounds__(128) void emb_kernel(const float* __restrict__ xb, const float* __restrict__ xv,
                                                  const float* __restrict__ Wb, const float* __restrict__ Wv,
                                                  u16* __restrict__ hb){
    __shared__ float xs[8][FB];
    int j = threadIdx.x;
    int n0 = blockIdx.x * 8;
    const float* x; const float* W; int K; int xoff;
    if (n0 < N_NODES){ x = xb; W = Wb; K = FB; xoff = n0; }
    else             { x = xv; W = Wv; K = FV; xoff = n0 - N_NODES; }
    for (int i = j; i < 8*K; i += 128){ int r = i / K, c = i - r*K; xs[r][c] = x[(xoff + r)*K + c]; }
    __syncthreads();
    float acc[8];
    #pragma unroll
    for (int n = 0; n < 8; ++n) acc[n] = 0.f;
    for (int k = 0; k < K; ++k){
        float w = W[k*H + j];
        #pragma unroll
        for (int n = 0; n < 8; ++n) acc[n] = fmaf(xs[n][k], w, acc[n]);
    }
    #pragma unroll
    for (int n = 0; n < 8; ++n)
        hb[(size_t)(n0 + n)*H + j] = f2bf(fmaxf(acc[n], 0.f));
}

// ---------------- agg_raw[dst] = sum hb[src] ----------------
// One wave per node. 16 lanes cover a row (uint4 = 16B/lane); 4 quarter-waves
// process 4 edges in parallel; 2x unroll -> 8 edges / loop iteration.

__global__ __launch_bounds__(256) void agg_kernel(const u16* __restrict__ hb,
                                                  const int* __restrict__ row_ptr,
                                                  const int* __restrict__ csr_src,
                                                  u16* __restrict__ aggb){
    int wid  = threadIdx.x >> 6;
    int lane = threadIdx.x & 63;
    int q    = lane >> 4;          // 0..3: edge slot
    int c    = lane & 15;          // uint4 index within the row
    int node = blockIdx.x*4 + wid;
    int beg = row_ptr[node], end = row_ptr[node+1];
    const uint4* rows = reinterpret_cast<const uint4*>(hb);
    float s0=0.f,s1=0.f,s2=0.f,s3=0.f,s4=0.f,s5=0.f,s6=0.f,s7=0.f;
    float u0=0.f,u1=0.f,u2=0.f,u3=0.f,u4=0.f,u5=0.f,u6=0.f,u7=0.f;
    int e = beg + q;
    for (; e + 4 < end; e += 8){
        int sA = csr_src[e];
        int sB = csr_src[e + 4];
        uint4 a = rows[(size_t)sA*16 + c];
        uint4 b = rows[(size_t)sB*16 + c];
        s0 += bf16_lo(a.x); s1 += bf16_hi(a.x); s2 += bf16_lo(a.y); s3 += bf16_hi(a.y);
        s4 += bf16_lo(a.z); s5 += bf16_hi(a.z); s6 += bf16_lo(a.w); s7 += bf16_hi(a.w);
        u0 += bf16_lo(b.x); u1 += bf16_hi(b.x); u2 += bf16_lo(b.y); u3 += bf16_hi(b.y);
        u4 += bf16_lo(b.z); u5 += bf16_hi(b.z); u6 += bf16_lo(b.w); u7 += bf16_hi(b.w);
    }
    if (e < end){
        int sA = csr_src[e];
        uint4 a = rows[(size_t)sA*16 + c];
        s0 += bf16_lo(a.x); s1 += bf16_hi(a.x); s2 += bf16_lo(a.y); s3 += bf16_hi(a.y);
        s4 += bf16_lo(a.z); s5 += bf16_hi(a.z); s6 += bf16_lo(a.w); s7 += bf16_hi(a.w);
    }
    s0 += u0; s1 += u1; s2 += u2; s3 += u3; s4 += u4; s5 += u5; s6 += u6; s7 += u7;
    s0 += __shfl_xor(s0, 16); s1 += __shfl_xor(s1, 16); s2 += __shfl_xor(s2, 16); s3 += __shfl_xor(s3, 16);
    s4 += __shfl_xor(s4, 16); s5 += __shfl_xor(s5, 16); s6 += __shfl_xor(s6, 16); s7 += __shfl_xor(s7, 16);
    s0 += __shfl_xor(s0, 32); s1 += __shfl_xor(s1, 32); s2 += __shfl_xor(s2, 32); s3 += __shfl_xor(s3, 32);
    s4 += __shfl_xor(s4, 32); s5 += __shfl_xor(s5, 32); s6 += __shfl_xor(s6, 32); s7 += __shfl_xor(s7, 32);
    if (q == 0){
        uint4 o;
        o.x = (unsigned)f2bf(s0) | ((unsigned)f2bf(s1) << 16);
        o.y = (unsigned)f2bf(s2) | ((unsigned)f2bf(s3) << 16);
        o.z = (unsigned)f2bf(s4) | ((unsigned)f2bf(s5) << 16);
        o.w = (unsigned)f2bf(s6) | ((unsigned)f2bf(s7) << 16);
        reinterpret_cast<uint4*>(aggb)[(size_t)node*16 + c] = o;
    }
}

// ---------------- fused GRU via MFMA (bf16 state, fast gate math) ----------------
// grid (NN/64, 2). Block: 64 rows x 256 B-cols. 16 acc tiles = 64 AGPR.
// B staged via async global_load_lds width=16 (lane-contiguous fragment-major
// layout matches the wave-uniform-base + lane*16 LDS constraint); A keeps the
// padded VGPR path (padding is incompatible with direct-to-LDS).

__global__ __launch_bounds__(256, 3) void gru_mfma_kernel(const u16* __restrict__ aggb,
                                                          const u16* __restrict__ hb_in,
                                                          u16* __restrict__ hb_out,
                                                          const u16* __restrict__ Wcat,  /* this step: [2][8][12][64][8] */
                                                          const float* __restrict__ b_ih,
                                                          const float* __restrict__ b_hh){
    __shared__ u16 Bs[WCAT_KC];      // 12 KB, fragment-major
    __shared__ u16 As[64*BSTR];      // 5 KB
    const int t = threadIdx.x;
    const int wid = t >> 6, lane = t & 63;
    const int l15 = lane & 15, l4 = lane >> 4;
    const int n0 = blockIdx.x * 64;
    const int b1 = blockIdx.y;
    const u16* Wsrc = Wcat + (size_t)b1*WCAT_HALF;

    floatx4 accR[4], accZ[4], accNi[4], accNh[4];
    #pragma unroll
    for (int i = 0; i < 4; ++i){
        accR[i] = (floatx4){0.f,0.f,0.f,0.f};  accZ[i]  = (floatx4){0.f,0.f,0.f,0.f};
        accNi[i] = (floatx4){0.f,0.f,0.f,0.f}; accNh[i] = (floatx4){0.f,0.f,0.f,0.f};
    }

    for (int kc = 0; kc < 8; ++kc){
        __syncthreads();
        {   // stage B: 768 x 16B, fragment-major
            const u16* src = Wsrc + (size_t)kc*WCAT_KC;
#if __has_builtin(__builtin_amdgcn_global_load_lds)
            #pragma unroll
            for (int p = 0; p < 3; ++p){
                int i = t + p*256;
                __builtin_amdgcn_global_load_lds(
                    (const __attribute__((address_space(1))) void*)(src + (size_t)i*8),
                    (__attribute__((address_space(3))) void*)(&Bs[i*8]), 16, 0, 0);
            }
#else
            #pragma unroll
            for (int p = 0; p < 3; ++p){
                int i = t + p*256;
                *reinterpret_cast<int4*>(&Bs[i*8]) = *reinterpret_cast<const int4*>(src + (size_t)i*8);
            }
#endif
        }
        {   // stage A: 64 rows x 32 shorts (padded LDS rows; VGPR path)
            int row = t >> 2, part = t & 3;
            const u16* srcA = (kc < 4) ? aggb : hb_in;
            const int4 v = *reinterpret_cast<const int4*>(srcA + (size_t)(n0 + row)*H + (kc & 3)*32 + part*8);
            *reinterpret_cast<int4*>(&As[row*BSTR + part*8]) = v;
        }
        __syncthreads();
        bf16x8 aF = *reinterpret_cast<const bf16x8*>(&As[(wid*16 + l15)*BSTR + l4*8]);
        if (kc < 4){
            #pragma unroll
            for (int j = 0; j < 4; ++j){
                bf16x8 bR = *reinterpret_cast<const bf16x8*>(&Bs[((0*4 + j)*64 + lane)*8]);
                bf16x8 bZ = *reinterpret_cast<const bf16x8*>(&Bs[((1*4 + j)*64 + lane)*8]);
                bf16x8 bN = *reinterpret_cast<const bf16x8*>(&Bs[((2*4 + j)*64 + lane)*8]);
                accR[j]  = __builtin_amdgcn_mfma_f32_16x16x32_bf16(aF, bR, accR[j], 0, 0, 0);
                accZ[j]  = __builtin_amdgcn_mfma_f32_16x16x32_bf16(aF, bZ, accZ[j], 0, 0, 0);
                accNi[j] = __builtin_amdgcn_mfma_f32_16x16x32_bf16(aF, bN, accNi[j], 0, 0, 0);
            }
        } else {
            #pragma unroll
            for (int j = 0; j < 4; ++j){
                bf16x8 bR = *reinterpret_cast<const bf16x8*>(&Bs[((0*4 + j)*64 + lane)*8]);
                bf16x8 bZ = *reinterpret_cast<const bf16x8*>(&Bs[((1*4 + j)*64 + lane)*8]);
                bf16x8 bN = *reinterpret_cast<const bf16x8*>(&Bs[((2*4 + j)*64 + lane)*8]);
                accR[j]  = __builtin_amdgcn_mfma_f32_16x16x32_bf16(aF, bR, accR[j], 0, 0, 0);
                accZ[j]  = __builtin_amdgcn_mfma_f32_16x16x32_bf16(aF, bZ, accZ[j], 0, 0, 0);
                accNh[j] = __builtin_amdgcn_mfma_f32_16x16x32_bf16(aF, bN, accNh[j], 0, 0, 0);
            }
        }
    }

    const int rowb = n0 + wid*16 + l4*4;
    #pragma unroll
    for (int jj = 0; jj < 4; ++jj){
        int col = (4*b1 + jj)*16 + l15;
        float br  = b_ih[col]       + b_hh[col];
        float bz  = b_ih[128 + col] + b_hh[128 + col];
        float bin = b_ih[256 + col];
        float bhn = b_hh[256 + col];
        #pragma unroll
        for (int rg = 0; rg < 4; ++rg){
            int row = rowb + rg;
            float r   = fsigmoid(accR[jj][rg] + br);
            float z   = fsigmoid(accZ[jj][rg] + bz);
            float nn_ = ftanh(accNi[jj][rg] + bin + r*(accNh[jj][rg] + bhn));
            float hold = bf16_lo((unsigned)hb_in[(size_t)row*H + col]);
            float hnew = (1.f - z)*nn_ + z*hold;
            hb_out[(size_t)row*H + col] = f2bf(hnew);
        }
    }
}

// ---------------- pooling (bf16 state in) ----------------

__global__ __launch_bounds__(128) void pool_kernel(const u16* __restrict__ hb,
                                                   const int* __restrict__ batch_b, const int* __restrict__ batch_v,
                                                   float* __restrict__ pool){
    int j  = threadIdx.x;
    int n0 = blockIdx.x * 32;
    bool voro = (n0 >= N_NODES);
    int colbase = voro ? 128 : 0;
    int gcur = -1; float acc = 0.f;
    for (int r = 0; r < 32; ++r){
        int node = n0 + r;
        int g = voro ? batch_v[node - N_NODES] : batch_b[node];
        if (g != gcur){
            if (gcur >= 0) atomicAdd(&pool[gcur*256 + colbase + j], acc);
            acc = 0.f; gcur = g;
        }
        acc += fmaxf(bf16_lo((unsigned)hb[(size_t)node*H + j]), 0.f);
    }
    if (gcur >= 0) atomicAdd(&pool[gcur*256 + colbase + j], acc);
}

__global__ __launch_bounds__(256) void cnt_kernel(const int* __restrict__ batch_b, const int* __restrict__ batch_v,
                                                  int* __restrict__ cnt){
    __shared__ int bins[128];
    int t = threadIdx.x;
    if (t < 128) bins[t] = 0;
    __syncthreads();
    int i = blockIdx.x*256 + t;
    if (i < NN){
        int g = (i < N_NODES) ? batch_b[i] : 64 + batch_v[i - N_NODES];
        atomicAdd(&bins[g], 1);
    }
    __syncthreads();
    if (t < 128 && bins[t] > 0) atomicAdd(&cnt[t], bins[t]);
}

// ---------------- output head ----------------

__global__ __launch_bounds__(256) void head_kernel(const float* __restrict__ pool, const int* __restrict__ cnt,
                                                   const float* __restrict__ W1, const float* __restrict__ b1,
                                                   const float* __restrict__ W2, const float* __restrict__ b2,
                                                   float* __restrict__ out){
    __shared__ float gs[256];
    __shared__ float wsum[4];
    int b = blockIdx.x, j = threadIdx.x;
    int c = (j < 128) ? cnt[b] : cnt[64 + b];
    float denom = (float)((c > 1) ? c : 1);
    gs[j] = pool[b*256 + j] / denom;
    __syncthreads();
    float acc = b1[j];
    for (int k = 0; k < 256; ++k) acc = fmaf(gs[k], W1[k*256 + j], acc);
    float y = fmaxf(acc, 0.f) * W2[j];
    #pragma unroll
    for (int off = 32; off > 0; off >>= 1) y += __shfl_down(y, off, 64);
    if ((j & 63) == 0) wsum[j >> 6] = y;
    __syncthreads();
    if (j == 0){
        float x = wsum[0] + wsum[1] + wsum[2] + wsum[3] + b2[0];
        float sp = (x > 0.f) ? x + log1pf(expf(-x)) : log1pf(expf(x));
        out[b] = sp;
    }
}

// ---------------- launch ----------------

extern "C" void kernel_launch(void* const* d_in, const int* in_sizes, int n_in,
                              void* d_out, int out_size, void* d_ws, size_t ws_size,
                              hipStream_t stream){
    const float* x_b      = (const float*)d_in[0];
    const int*   eib      = (const int*)  d_in[1];
    const int*   batch_b  = (const int*)  d_in[2];
    const float* x_v      = (const float*)d_in[3];
    const int*   eiv      = (const int*)  d_in[4];
    const int*   batch_v  = (const int*)  d_in[5];
    const float* W_emb_b  = (const float*)d_in[6];
    const float* W_emb_v  = (const float*)d_in[7];
    const float* ggc_w    = (const float*)d_in[8];
    const float* gru_w_ih = (const float*)d_in[9];
    const float* gru_w_hh = (const float*)d_in[10];
    const float* gru_b_ih = (const float*)d_in[11];
    const float* gru_b_hh = (const float*)d_in[12];
    const float* W1       = (const float*)d_in[13];
    const float* b1       = (const float*)d_in[14];
    const float* W2       = (const float*)d_in[15];
    const float* b2       = (const float*)d_in[16];
    float* out = (float*)d_out;

    char* ws = (char*)d_ws;
    size_t off = 0;
    auto alloc = [&](size_t bytes)->char*{
        char* p = ws + off; off += (bytes + 255)/256*256; return p;
    };
    u16*   hb0      = (u16*)   alloc((size_t)NN*H*2);        //  51.2 MB
    u16*   hb1      = (u16*)   alloc((size_t)NN*H*2);        //  51.2 MB
    u16*   aggb     = (u16*)   alloc((size_t)NN*H*2);        //  51.2 MB
    float* Bfold    = (float*) alloc((size_t)STEPS*H*384*4); // 786 KB
    u16*   Wcat     = (u16*)   alloc((size_t)STEPS*WCAT_STEP*2);
    int*   row_ptr  = (int*)   alloc((size_t)(NN+1)*4);
    int*   deg      = (int*)   alloc((size_t)NNP*4);
    int*   cursor   = (int*)   alloc((size_t)NN*4);
    int*   csr_src  = (int*)   alloc((size_t)EE*4);
    int*   bsum     = (int*)   alloc((size_t)256*4);
    int*   boff     = (int*)   alloc((size_t)256*4);
    float* pool     = (float*) alloc((size_t)NG*2*H*4);
    int*   cnt      = (int*)   alloc((size_t)2*NG*4);
    (void)ws_size; (void)in_sizes; (void)n_in; (void)out_size;

    hipMemsetAsync(deg,  0, (size_t)NNP*4, stream);
    hipMemsetAsync(pool, 0, (size_t)NG*2*H*4, stream);
    hipMemsetAsync(cnt,  0, (size_t)2*NG*4, stream);

    deg_kernel        <<<(EE + 255)/256, 256, 0, stream>>>(eib, eiv, deg);
    bsum_kernel       <<<NBLK, 256, 0, stream>>>(deg, bsum);
    bscan_kernel      <<<1, 256, 0, stream>>>(bsum, boff);
    scan_final_kernel <<<NBLK, 256, 0, stream>>>(deg, boff, row_ptr, cursor);
    csr_fill_kernel   <<<(EE + 255)/256, 256, 0, stream>>>(eib, eiv, cursor, csr_src);
    fold_kernel       <<<STEPS*H, 128, 0, stream>>>(ggc_w, gru_w_ih, Bfold);
    pack_kernel       <<<(STEPS*WCAT_STEP + 255)/256, 256, 0, stream>>>(Bfold, gru_w_hh, Wcat);

    emb_kernel<<<NN/8, 128, 0, stream>>>(x_b, x_v, W_emb_b, W_emb_v, hb0);

    u16* hbs[2] = { hb0, hb1 };
    for (int s = 0; s < STEPS; ++s){
        u16* hin  = hbs[s & 1];
        u16* hout = hbs[(s + 1) & 1];
        agg_kernel     <<<NN/4, 256, 0, stream>>>(hin, row_ptr, csr_src, aggb);
        gru_mfma_kernel<<<dim3(NN/64, 2), 256, 0, stream>>>(aggb, hin, hout,
                                                            Wcat + (size_t)s*WCAT_STEP,
                                                            gru_b_ih, gru_b_hh);
    }

    pool_kernel<<<NN/32, 128, 0, stream>>>(hb0, batch_b, batch_v, pool);
    cnt_kernel <<<(NN + 255)/256, 256, 0, stream>>>(batch_b, batch_v, cnt);
    head_kernel<<<NG, 256, 0, stream>>>(pool, cnt, W1, b1, W2, b2, out);
}